// Round 1
// baseline (157.794 us; speedup 1.0000x reference)
//
#include <hip/hip_runtime.h>

// BaconAdditionReasoner: y[b,k] = norm_k( 1 - prod_{i+j==k} (1 - clamp(min(p1p_i, p2p_j))) )
// where p1p = p1 @ minmax_norm(W1), p2p = p2 @ minmax_norm(W2).
// Direct product replaces exp(sum(log(.))) — mathematically identical, avoids transcendentals.

#define ROWS_PER_BLOCK 256
#define NBLOCKS 4096  // 4096 * 256 = 1048576 = B

// Normalize W1, W2 rows (minmax over axis=1) into ws[0..100) and ws[100..200).
__global__ void prep_normW(const float* __restrict__ W1,
                           const float* __restrict__ W2,
                           float* __restrict__ wn) {
    int t = threadIdx.x;
    if (t < 20) {
        const float* W = (t < 10) ? W1 : W2;
        int r = t % 10;
        const float* row = W + r * 10;
        float lo = row[0], hi = row[0];
        #pragma unroll
        for (int i = 1; i < 10; ++i) {
            lo = fminf(lo, row[i]);
            hi = fmaxf(hi, row[i]);
        }
        float inv = 1.0f / (hi - lo + 1e-8f);
        float* o = wn + ((t < 10) ? 0 : 100) + r * 10;
        #pragma unroll
        for (int i = 0; i < 10; ++i) o[i] = (row[i] - lo) * inv;
    }
}

__global__ __launch_bounds__(256) void bacon_main(
    const float* __restrict__ p1, const float* __restrict__ p2,
    const float* __restrict__ wn, float* __restrict__ out)
{
    // 20480 B LDS: input staging (2 x 2560 floats), reused for output staging (4864 floats)
    __shared__ __align__(16) float lds[5120];
    const int t = threadIdx.x;
    const int blk = blockIdx.x;

    // ---- stage p1/p2 tiles: 2560 floats each = 640 float4, coalesced ----
    {
        const float4* g1 = (const float4*)(p1 + (size_t)blk * 2560);
        const float4* g2 = (const float4*)(p2 + (size_t)blk * 2560);
        float4* s1 = (float4*)lds;
        float4* s2 = (float4*)(lds + 2560);
        #pragma unroll
        for (int it = 0; it < 3; ++it) {
            int idx = t + it * 256;
            if (idx < 640) { s1[idx] = g1[idx]; s2[idx] = g2[idx]; }
        }
    }
    __syncthreads();

    // ---- each thread reads its own row (10 floats each input) ----
    float a[10], b[10];
    {
        const float* r1 = lds + t * 10;
        const float* r2 = lds + 2560 + t * 10;
        #pragma unroll
        for (int e = 0; e < 10; ++e) { a[e] = r1[e]; b[e] = r2[e]; }
    }

    // ---- p1p = a @ W1n, p2p = b @ W2n (W from scalar cache, wave-uniform) ----
    float ap[10], bp[10];
    #pragma unroll
    for (int i = 0; i < 10; ++i) { ap[i] = 0.0f; bp[i] = 0.0f; }
    #pragma unroll
    for (int k = 0; k < 10; ++k) {
        #pragma unroll
        for (int i = 0; i < 10; ++i) {
            ap[i] = fmaf(a[k], wn[k * 10 + i],       ap[i]);
            bp[i] = fmaf(b[k], wn[100 + k * 10 + i], bp[i]);
        }
    }

    // ---- graded AND over all pairs, direct product per sum-bin ----
    float prod[19];
    #pragma unroll
    for (int k = 0; k < 19; ++k) prod[k] = 1.0f;
    #pragma unroll
    for (int i = 0; i < 10; ++i) {
        #pragma unroll
        for (int j = 0; j < 10; ++j) {
            float s  = fminf(ap[i], bp[j]);
            float om = 1.0f - s;                  // == 1 - clip(s) after clamp below
            om = fminf(fmaxf(om, 1e-6f), 1.0f - 1e-6f);
            prod[i + j] *= om;
        }
    }

    // ---- y = 1 - prod, normalize ----
    float y[19];
    float tot = 0.0f;
    #pragma unroll
    for (int k = 0; k < 19; ++k) { y[k] = 1.0f - prod[k]; tot += y[k]; }
    float inv = 1.0f / (tot + 1e-9f);

    // ---- stage output in LDS (stride 19 is odd -> conflict-free), store coalesced ----
    __syncthreads();   // all input-row LDS reads complete before overwrite
    #pragma unroll
    for (int k = 0; k < 19; ++k) lds[t * 19 + k] = y[k] * inv;
    __syncthreads();

    {
        const float4* so = (const float4*)lds;                       // 1216 float4
        float4* go = (float4*)(out + (size_t)blk * 4864);            // 19456 B, 16-aligned
        #pragma unroll
        for (int it = 0; it < 5; ++it) {
            int idx = t + it * 256;
            if (idx < 1216) go[idx] = so[idx];
        }
    }
}

extern "C" void kernel_launch(void* const* d_in, const int* in_sizes, int n_in,
                              void* d_out, int out_size, void* d_ws, size_t ws_size,
                              hipStream_t stream) {
    const float* p1 = (const float*)d_in[0];
    const float* p2 = (const float*)d_in[1];
    const float* W1 = (const float*)d_in[2];
    const float* W2 = (const float*)d_in[3];
    // d_in[4] = mask: bins are i+j, computed directly — mask unused.
    float* wn = (float*)d_ws;   // 200 floats of scratch

    prep_normW<<<1, 64, 0, stream>>>(W1, W2, wn);
    bacon_main<<<NBLOCKS, 256, 0, stream>>>(p1, p2, wn, (float*)d_out);
}

// Round 2
// 152.845 us; speedup vs baseline: 1.0324x; 1.0324x over previous
//
#include <hip/hip_runtime.h>

// BaconAdditionReasoner: y[b,k] = norm_k( 1 - prod_{i+j==k} (1 - clamp(min(p1p_i, p2p_j))) )
// where p1p = p1 @ minmax_norm(W1), p2p = p2 @ minmax_norm(W2).
//
// R2 algebra: 1 - min(ap_i, bp_j) = max(1-ap_i, 1-bp_j). We accumulate
// A_i = 1 - sum_k a_k wn[k][i] directly in the matmul (fma with -a_k, init 1.0),
// so the pair loop is just prod[i+j] *= max(A_i, B_j)  (2 VALU ops/pair).
// Clamps to [1e-6, 1-1e-6] are dropped: s is provably in [0,1] (p rows sum to 1,
// wn in [0,1]), so clamping perturbs y by <= ~1e-5 — far below the 1.34e-3
// threshold (round-1 margin was 2.7x).
// R2 structure: direct strided global loads (rows are 8B-aligned, L3-resident)
// replace the LDS input staging + first barrier — waves no longer convoy.

#define NBLOCKS 4096  // 4096 * 256 = 1048576 = B

// Normalize W1, W2 rows (minmax over axis=1) into ws[0..100) and ws[100..200).
__global__ void prep_normW(const float* __restrict__ W1,
                           const float* __restrict__ W2,
                           float* __restrict__ wn) {
    int t = threadIdx.x;
    if (t < 20) {
        const float* W = (t < 10) ? W1 : W2;
        int r = t % 10;
        const float* row = W + r * 10;
        float lo = row[0], hi = row[0];
        #pragma unroll
        for (int i = 1; i < 10; ++i) {
            lo = fminf(lo, row[i]);
            hi = fmaxf(hi, row[i]);
        }
        float inv = 1.0f / (hi - lo + 1e-8f);
        float* o = wn + ((t < 10) ? 0 : 100) + r * 10;
        #pragma unroll
        for (int i = 0; i < 10; ++i) o[i] = (row[i] - lo) * inv;
    }
}

__global__ __launch_bounds__(256, 8) void bacon_main(
    const float* __restrict__ p1, const float* __restrict__ p2,
    const float* __restrict__ wn, float* __restrict__ out)
{
    // LDS only for output coalescing: 4864 floats = 19456 B -> 8 blocks/CU
    __shared__ __align__(16) float lds[4864];
    const int t = threadIdx.x;
    const int blk = blockIdx.x;

    // ---- direct per-row loads: 5x dwordx2 per input (row = 40 B, 8B-aligned) ----
    float a[10], b[10];
    {
        const float2* g1 = (const float2*)p1 + (size_t)blk * 1280 + t * 5;
        const float2* g2 = (const float2*)p2 + (size_t)blk * 1280 + t * 5;
        #pragma unroll
        for (int e = 0; e < 5; ++e) {
            float2 v1 = g1[e];
            float2 v2 = g2[e];
            a[2 * e] = v1.x; a[2 * e + 1] = v1.y;
            b[2 * e] = v2.x; b[2 * e + 1] = v2.y;
        }
    }

    // ---- A_i = 1 - a @ W1n, B_j = 1 - b @ W2n (wn via scalar cache, wave-uniform) ----
    float A[10], Bv[10];
    #pragma unroll
    for (int i = 0; i < 10; ++i) { A[i] = 1.0f; Bv[i] = 1.0f; }
    #pragma unroll
    for (int k = 0; k < 10; ++k) {
        #pragma unroll
        for (int i = 0; i < 10; ++i) {
            A[i]  = fmaf(-a[k], wn[k * 10 + i],       A[i]);
            Bv[i] = fmaf(-b[k], wn[100 + k * 10 + i], Bv[i]);
        }
    }

    // ---- per sum-bin product of (1 - min) == max(A_i, B_j): 2 ops/pair ----
    float prod[19];
    #pragma unroll
    for (int k = 0; k < 19; ++k) prod[k] = 1.0f;
    #pragma unroll
    for (int i = 0; i < 10; ++i) {
        #pragma unroll
        for (int j = 0; j < 10; ++j) {
            prod[i + j] *= fmaxf(A[i], Bv[j]);
        }
    }

    // ---- y = 1 - prod, normalize (approx rcp: rel err ~1e-7, fine) ----
    float y[19];
    float tot = 0.0f;
    #pragma unroll
    for (int k = 0; k < 19; ++k) { y[k] = 1.0f - prod[k]; tot += y[k]; }
    float inv = __builtin_amdgcn_rcpf(tot + 1e-9f);

    // ---- stage output in LDS (stride 19 odd -> 2-way aliasing, free), store float4 ----
    #pragma unroll
    for (int k = 0; k < 19; ++k) lds[t * 19 + k] = y[k] * inv;
    __syncthreads();

    {
        const float4* so = (const float4*)lds;                 // 1216 float4
        float4* go = (float4*)(out + (size_t)blk * 4864);      // 19456 B, 16-aligned
        #pragma unroll
        for (int it = 0; it < 5; ++it) {
            int idx = t + it * 256;
            if (idx < 1216) go[idx] = so[idx];
        }
    }
}

extern "C" void kernel_launch(void* const* d_in, const int* in_sizes, int n_in,
                              void* d_out, int out_size, void* d_ws, size_t ws_size,
                              hipStream_t stream) {
    const float* p1 = (const float*)d_in[0];
    const float* p2 = (const float*)d_in[1];
    const float* W1 = (const float*)d_in[2];
    const float* W2 = (const float*)d_in[3];
    // d_in[4] = mask: bins are i+j, computed directly — mask unused.
    float* wn = (float*)d_ws;   // 200 floats of scratch

    prep_normW<<<1, 64, 0, stream>>>(W1, W2, wn);
    bacon_main<<<NBLOCKS, 256, 0, stream>>>(p1, p2, wn, (float*)d_out);
}

// Round 3
// 151.516 us; speedup vs baseline: 1.0414x; 1.0088x over previous
//
#include <hip/hip_runtime.h>

// BaconAdditionReasoner: y[b,k] = norm_k( 1 - prod_{i+j==k} (1 - clamp(min(p1p_i, p2p_j))) )
// where p1p = p1 @ minmax_norm(W1), p2p = p2 @ minmax_norm(W2).
//
// R2 algebra (kept): 1 - min(ap_i, bp_j) = max(1-ap_i, 1-bp_j); A_i = 1 - a@W1n
// computed directly in the matmul; clamps dropped (s provably in [0,1], error
// << threshold). Pair loop = 2 VALU ops/pair.
//
// R3 change: __launch_bounds__(256, 4) instead of (256, 8). The (256,8) cap
// forced a <=64-VGPR budget; the ~45-reg live set (A+Bv+prod) spilled to
// scratch, creating ~100 dependent ~300-cyc spill-reload chains per wave
// (~33k stall cycles — the measured per-wave residency). 128-VGPR budget
// holds everything in registers. // VGPR_Count must jump from 32 to ~80+.

#define NBLOCKS 4096  // 4096 * 256 = 1048576 = B

// Normalize W1, W2 rows (minmax over axis=1) into ws[0..100) and ws[100..200).
__global__ void prep_normW(const float* __restrict__ W1,
                           const float* __restrict__ W2,
                           float* __restrict__ wn) {
    int t = threadIdx.x;
    if (t < 20) {
        const float* W = (t < 10) ? W1 : W2;
        int r = t % 10;
        const float* row = W + r * 10;
        float lo = row[0], hi = row[0];
        #pragma unroll
        for (int i = 1; i < 10; ++i) {
            lo = fminf(lo, row[i]);
            hi = fmaxf(hi, row[i]);
        }
        float inv = 1.0f / (hi - lo + 1e-8f);
        float* o = wn + ((t < 10) ? 0 : 100) + r * 10;
        #pragma unroll
        for (int i = 0; i < 10; ++i) o[i] = (row[i] - lo) * inv;
    }
}

__global__ __launch_bounds__(256, 4) void bacon_main(
    const float* __restrict__ p1, const float* __restrict__ p2,
    const float* __restrict__ wn, float* __restrict__ out)
{
    // LDS only for output coalescing: 4864 floats = 19456 B
    __shared__ __align__(16) float lds[4864];
    const int t = threadIdx.x;
    const int blk = blockIdx.x;

    // ---- direct per-row loads: 5x dwordx2 per input (row = 40 B, 8B-aligned) ----
    float a[10], b[10];
    {
        const float2* g1 = (const float2*)p1 + (size_t)blk * 1280 + t * 5;
        const float2* g2 = (const float2*)p2 + (size_t)blk * 1280 + t * 5;
        #pragma unroll
        for (int e = 0; e < 5; ++e) {
            float2 v1 = g1[e];
            float2 v2 = g2[e];
            a[2 * e] = v1.x; a[2 * e + 1] = v1.y;
            b[2 * e] = v2.x; b[2 * e + 1] = v2.y;
        }
    }

    // ---- A_i = 1 - a @ W1n, B_j = 1 - b @ W2n (wn via scalar cache, wave-uniform) ----
    float A[10], Bv[10];
    #pragma unroll
    for (int i = 0; i < 10; ++i) { A[i] = 1.0f; Bv[i] = 1.0f; }
    #pragma unroll
    for (int k = 0; k < 10; ++k) {
        #pragma unroll
        for (int i = 0; i < 10; ++i) {
            A[i]  = fmaf(-a[k], wn[k * 10 + i],       A[i]);
            Bv[i] = fmaf(-b[k], wn[100 + k * 10 + i], Bv[i]);
        }
    }

    // ---- per sum-bin product of (1 - min) == max(A_i, B_j): 2 ops/pair ----
    float prod[19];
    #pragma unroll
    for (int k = 0; k < 19; ++k) prod[k] = 1.0f;
    #pragma unroll
    for (int i = 0; i < 10; ++i) {
        #pragma unroll
        for (int j = 0; j < 10; ++j) {
            prod[i + j] *= fmaxf(A[i], Bv[j]);
        }
    }

    // ---- y = 1 - prod, normalize (approx rcp: rel err ~1e-7, fine) ----
    float y[19];
    float tot = 0.0f;
    #pragma unroll
    for (int k = 0; k < 19; ++k) { y[k] = 1.0f - prod[k]; tot += y[k]; }
    float inv = __builtin_amdgcn_rcpf(tot + 1e-9f);

    // ---- stage output in LDS (stride 19 odd -> 2-way aliasing, free), store float4 ----
    #pragma unroll
    for (int k = 0; k < 19; ++k) lds[t * 19 + k] = y[k] * inv;
    __syncthreads();

    {
        const float4* so = (const float4*)lds;                 // 1216 float4
        float4* go = (float4*)(out + (size_t)blk * 4864);      // 19456 B, 16-aligned
        #pragma unroll
        for (int it = 0; it < 5; ++it) {
            int idx = t + it * 256;
            if (idx < 1216) go[idx] = so[idx];
        }
    }
}

extern "C" void kernel_launch(void* const* d_in, const int* in_sizes, int n_in,
                              void* d_out, int out_size, void* d_ws, size_t ws_size,
                              hipStream_t stream) {
    const float* p1 = (const float*)d_in[0];
    const float* p2 = (const float*)d_in[1];
    const float* W1 = (const float*)d_in[2];
    const float* W2 = (const float*)d_in[3];
    // d_in[4] = mask: bins are i+j, computed directly — mask unused.
    float* wn = (float*)d_ws;   // 200 floats of scratch

    prep_normW<<<1, 64, 0, stream>>>(W1, W2, wn);
    bacon_main<<<NBLOCKS, 256, 0, stream>>>(p1, p2, wn, (float*)d_out);
}

// Round 4
// 150.471 us; speedup vs baseline: 1.0487x; 1.0069x over previous
//
#include <hip/hip_runtime.h>

// BaconAdditionReasoner: y[b,k] = norm_k( 1 - prod_{i+j==k} (1 - clamp(min(p1p_i, p2p_j))) )
// where p1p = p1 @ minmax_norm(W1), p2p = p2 @ minmax_norm(W2).
//
// R2 algebra (kept): 1 - min(ap_i,bp_j) = max(1-ap_i, 1-bp_j); A_i = 1 - a@W1n
// folded into the matmul; clamps dropped (s in [0,1], error << threshold).
//
// R4: wn moved from global (scalar-cache) to LDS. 200 uniform floats don't fit
// in SGPRs, so rounds 1-3 paid ~13 serialized s_load->lgkmcnt->consume chains
// per wave (~3-5k unhideable cycles — the common factor behind the flat 47us).
// LDS broadcast ds_read_b128 (same-address, conflict-free) pipelines instead.
// Prep is fused: threads 0..19 of every block compute wn into LDS (trivial),
// removing the separate prep dispatch from the graph.

#define NBLOCKS 4096  // 4096 * 256 = 1048576 = B

__global__ __launch_bounds__(256) void bacon_main(
    const float* __restrict__ p1, const float* __restrict__ p2,
    const float* __restrict__ W1, const float* __restrict__ W2,
    float* __restrict__ out)
{
    __shared__ __align__(16) float s_out[4864];      // output coalescing stage
    __shared__ __align__(16) float s_w[240];         // wn: [2][10][12] stride-12 padded

    const int t = threadIdx.x;
    const int blk = blockIdx.x;

    // ---- issue own-row global loads first (longest latency, no deps) ----
    float a[10], b[10];
    {
        const float2* g1 = (const float2*)p1 + (size_t)blk * 1280 + t * 5;
        const float2* g2 = (const float2*)p2 + (size_t)blk * 1280 + t * 5;
        #pragma unroll
        for (int e = 0; e < 5; ++e) {
            float2 v1 = g1[e];
            float2 v2 = g2[e];
            a[2 * e] = v1.x; a[2 * e + 1] = v1.y;
            b[2 * e] = v2.x; b[2 * e + 1] = v2.y;
        }
    }

    // ---- fused prep: threads 0..19 minmax-normalize one W row into LDS ----
    if (t < 20) {
        const float* row = ((t < 10) ? W1 : W2) + (t % 10) * 10;
        float r[10];
        #pragma unroll
        for (int i = 0; i < 10; ++i) r[i] = row[i];
        float lo = r[0], hi = r[0];
        #pragma unroll
        for (int i = 1; i < 10; ++i) {
            lo = fminf(lo, r[i]);
            hi = fmaxf(hi, r[i]);
        }
        float inv = 1.0f / (hi - lo + 1e-8f);
        float* o = s_w + ((t < 10) ? 0 : 120) + (t % 10) * 12;
        #pragma unroll
        for (int i = 0; i < 10; ++i) o[i] = (r[i] - lo) * inv;
        o[10] = 0.0f; o[11] = 0.0f;  // init pad (never multiplied, but keep clean)
    }
    __syncthreads();

    // ---- A_i = 1 - a @ W1n, B_j = 1 - b @ W2n; wn via LDS broadcast float4 ----
    float A[10], Bv[10];
    #pragma unroll
    for (int i = 0; i < 10; ++i) { A[i] = 1.0f; Bv[i] = 1.0f; }
    #pragma unroll
    for (int k = 0; k < 10; ++k) {
        float ak = a[k], bk = b[k];
        const float4* w1q = (const float4*)(s_w + k * 12);          // 48B-aligned
        const float4* w2q = (const float4*)(s_w + 120 + k * 12);
        float4 u0 = w1q[0], u1 = w1q[1];
        float2 u2 = *(const float2*)(s_w + k * 12 + 8);
        float4 v0 = w2q[0], v1 = w2q[1];
        float2 v2 = *(const float2*)(s_w + 120 + k * 12 + 8);
        A[0] = fmaf(-ak, u0.x, A[0]); A[1] = fmaf(-ak, u0.y, A[1]);
        A[2] = fmaf(-ak, u0.z, A[2]); A[3] = fmaf(-ak, u0.w, A[3]);
        A[4] = fmaf(-ak, u1.x, A[4]); A[5] = fmaf(-ak, u1.y, A[5]);
        A[6] = fmaf(-ak, u1.z, A[6]); A[7] = fmaf(-ak, u1.w, A[7]);
        A[8] = fmaf(-ak, u2.x, A[8]); A[9] = fmaf(-ak, u2.y, A[9]);
        Bv[0] = fmaf(-bk, v0.x, Bv[0]); Bv[1] = fmaf(-bk, v0.y, Bv[1]);
        Bv[2] = fmaf(-bk, v0.z, Bv[2]); Bv[3] = fmaf(-bk, v0.w, Bv[3]);
        Bv[4] = fmaf(-bk, v1.x, Bv[4]); Bv[5] = fmaf(-bk, v1.y, Bv[5]);
        Bv[6] = fmaf(-bk, v1.z, Bv[6]); Bv[7] = fmaf(-bk, v1.w, Bv[7]);
        Bv[8] = fmaf(-bk, v2.x, Bv[8]); Bv[9] = fmaf(-bk, v2.y, Bv[9]);
    }

    // ---- per sum-bin product of (1 - min) == max(A_i, B_j): 2 ops/pair ----
    float prod[19];
    #pragma unroll
    for (int k = 0; k < 19; ++k) prod[k] = 1.0f;
    #pragma unroll
    for (int i = 0; i < 10; ++i) {
        #pragma unroll
        for (int j = 0; j < 10; ++j) {
            prod[i + j] *= fmaxf(A[i], Bv[j]);
        }
    }

    // ---- y = 1 - prod, normalize ----
    float y[19];
    float tot = 0.0f;
    #pragma unroll
    for (int k = 0; k < 19; ++k) { y[k] = 1.0f - prod[k]; tot += y[k]; }
    float inv = __builtin_amdgcn_rcpf(tot + 1e-9f);

    // ---- stage output in LDS (stride 19 odd -> 2-way aliasing, free), store float4 ----
    #pragma unroll
    for (int k = 0; k < 19; ++k) s_out[t * 19 + k] = y[k] * inv;
    __syncthreads();

    {
        const float4* so = (const float4*)s_out;               // 1216 float4
        float4* go = (float4*)(out + (size_t)blk * 4864);      // 19456 B, 16-aligned
        #pragma unroll
        for (int it = 0; it < 5; ++it) {
            int idx = t + it * 256;
            if (idx < 1216) go[idx] = so[idx];
        }
    }
}

extern "C" void kernel_launch(void* const* d_in, const int* in_sizes, int n_in,
                              void* d_out, int out_size, void* d_ws, size_t ws_size,
                              hipStream_t stream) {
    const float* p1 = (const float*)d_in[0];
    const float* p2 = (const float*)d_in[1];
    const float* W1 = (const float*)d_in[2];
    const float* W2 = (const float*)d_in[3];
    // d_in[4] = mask: bins are i+j, computed directly — mask unused.
    bacon_main<<<NBLOCKS, 256, 0, stream>>>(p1, p2, W1, W2, (float*)d_out);
}